// Round 5
// baseline (731.765 us; speedup 1.0000x reference)
//
#include <hip/hip_runtime.h>
#include <hip/hip_bf16.h>

// ---- problem constants ----
#define H 2048
#define NH 16
#define NOPE 128
#define ROPE_D 64
#define DQK 192      // NOPE + ROPE
#define VD 128
#define QL 1536
#define KVL 512
#define NE 8
#define MI_D 512
#define SHI 1024     // SH_I = 2*MI
#define EPS 1e-6f
#define MAXA 5120    // max padded MoE assignments

typedef unsigned short bfu;   // raw bf16 bits
typedef short bf16x8 __attribute__((ext_vector_type(8)));
typedef float f32x4 __attribute__((ext_vector_type(4)));

#define MFMA16(a, b, c) __builtin_amdgcn_mfma_f32_16x16x32_bf16(a, b, c, 0, 0, 0)

// raw barriers: avoid the compiler's s_waitcnt vmcnt(0) drain before s_barrier
#define BAR_PLAIN()   asm volatile("s_barrier" ::: "memory")
#define BAR_LGKM0()   asm volatile("s_waitcnt lgkmcnt(0)\n\ts_barrier" ::: "memory")
#define BAR_VM8L0()   asm volatile("s_waitcnt vmcnt(8) lgkmcnt(0)\n\ts_barrier" ::: "memory")
#define BAR_VM2L0()   asm volatile("s_waitcnt vmcnt(2) lgkmcnt(0)\n\ts_barrier" ::: "memory")
#define BAR_VM0L0()   asm volatile("s_waitcnt vmcnt(0) lgkmcnt(0)\n\ts_barrier" ::: "memory")

__device__ __forceinline__ float bf2f(bfu u) {
    union { unsigned int i; float f; } w; w.i = ((unsigned int)u) << 16; return w.f;
}
__device__ __forceinline__ bfu f2bf(float f) {
    union { float f; unsigned int i; } u; u.f = f;
    return (bfu)((u.i + 0x7fffu + ((u.i >> 16) & 1u)) >> 16);
}
// HW packed f32->bf16 (RNE), gfx950-verified; dst = {hi:bf16(s1), lo:bf16(s0)}
__device__ __forceinline__ unsigned pk2(float lo, float hi) {
    unsigned r; asm("v_cvt_pk_bf16_f32 %0, %1, %2" : "=v"(r) : "v"(lo), "v"(hi)); return r;
}

__device__ __forceinline__ void async16(const bfu* g, bfu* l) {
    __builtin_amdgcn_global_load_lds((const __attribute__((address_space(1))) void*)g,
                                     (__attribute__((address_space(3))) void*)l, 16, 0, 0);
}

// bijective XCD-chunk swizzle (m204 form)
__device__ __forceinline__ int xcd_swz(int b, int nt) {
    int q = nt >> 3, r = nt & 7;
    int x = b & 7, o = b >> 3;
    int base = (x < r) ? x * (q + 1) : r * (q + 1) + (x - r) * q;
    return base + o;
}

// block-wide sum over 256 threads (4 waves of 64)
__device__ __forceinline__ float blk_sum(float v) {
    __shared__ float sb[4];
    for (int o = 32; o > 0; o >>= 1) v += __shfl_down(v, o, 64);
    int lane = threadIdx.x & 63, w = threadIdx.x >> 6;
    __syncthreads();
    if (lane == 0) sb[w] = v;
    __syncthreads();
    return sb[0] + sb[1] + sb[2] + sb[3];
}

// ========== MFMA GEMM: C[M,N] = A[M,K]bf16 @ W[N,K]^T(f32, cast-on-stage) ==========
// A: global_load_lds 3-ring, distance 2. B: reg-staged f32 -> cvt_pk bf16 -> LDS
// (2 slots; write iter it+1's tile while computing it; loads issued 1 iter ahead).
// No separate weight-cast pass: saves 281MB cast traffic + a 90us dispatch.
// mode 0: f32 store; 1: bf16 store; 4: split (n0<2048 bf16 C, else V^T via LDS transpose).
struct GemmSeg {
    const bfu* A; const float* B0; const float* B1; void* C; void* C2;
    const int* aidx; const int* eid;
    long bstride;
    int N, K, ldm3, mode, nx, ntiles, nsplit, npad;
};

__device__ __forceinline__ void gemm_body(const bfu* __restrict__ A,
                                          const float* __restrict__ B0f,
                                          const float* __restrict__ B1f,
                                          void* __restrict__ Cv, void* __restrict__ Cv2,
                                          int N, int K, int ldm3, int mode,
                                          int nsplit, int npad,
                                          const int* __restrict__ aidx,
                                          const int* __restrict__ eid, long bstride,
                                          int bx, int by,
                                          bfu* sAb, bfu* sBb) {
    bfu (*sA)[128 * 32] = (bfu (*)[128 * 32])sAb;
    bfu (*sB)[128 * 32] = (bfu (*)[128 * 32])sBb;
    const int tid = threadIdx.x;
    const int lane = tid & 63, w = tid >> 6;
    const int quad = lane >> 4, li = lane & 15;
    const int m0 = by * 128, n0 = bx * 128;

    const int l4 = lane >> 2;              // row within 16
    const int kc = (lane & 3) ^ ((lane >> 3) & 3); // swizzled source chunk
    int r0 = m0 + w * 32 + l4, r1 = r0 + 16;
    if (aidx) { r0 = aidx[r0]; r1 = aidx[r1]; }
    const bfu* gA0 = A + (size_t)r0 * K + kc * 8;
    const bfu* gA1 = A + (size_t)r1 * K + kc * 8;
    const int oA0 = (w * 32) * 32, oA1 = (w * 32 + 16) * 32;

    // f32 weight row pointers for B, with two-tensor split + zero-pad rows
    const int rb0 = n0 + w * 32 + l4, rb1 = rb0 + 16;
    bool z0 = false, z1 = false;
    const float* bp0;
    const float* bp1;
    if (eid) {
        const float* Be = B0f + (size_t)eid[by] * bstride;
        bp0 = Be + (size_t)rb0 * K + kc * 8;
        bp1 = Be + (size_t)rb1 * K + kc * 8;
    } else {
        z0 = rb0 >= npad; z1 = rb1 >= npad;
        bp0 = ((rb0 < nsplit) ? B0f + (size_t)rb0 * K : B1f + (size_t)(rb0 - nsplit) * K) + kc * 8;
        bp1 = ((rb1 < nsplit) ? B0f + (size_t)rb1 * K : B1f + (size_t)(rb1 - nsplit) * K) + kc * 8;
    }

    const int wm = (w >> 1) * 64, wn = (w & 1) * 64;
    const int fg = (quad ^ ((li >> 1) & 3)) * 8;
    int oa[4], ob[4];
#pragma unroll
    for (int t4 = 0; t4 < 4; ++t4) {
        oa[t4] = (wm + t4 * 16 + li) * 32 + fg;
        ob[t4] = (wn + t4 * 16 + li) * 32 + fg;
    }
    f32x4 acc[4][4];
#pragma unroll
    for (int i = 0; i < 4; ++i)
#pragma unroll
        for (int j = 0; j < 4; ++j) acc[i][j] = (f32x4){0.f, 0.f, 0.f, 0.f};

    const int nb = K / 32;
    float4 r00, r01, r10, r11;
#define LOADB(kt) do {                                                          \
        const float* q0_ = bp0 + (size_t)(kt) * 32;                             \
        const float* q1_ = bp1 + (size_t)(kt) * 32;                             \
        if (!z0) { r00 = *(const float4*)q0_; r01 = *(const float4*)(q0_ + 4); }\
        else { r00 = (float4){0.f,0.f,0.f,0.f}; r01 = (float4){0.f,0.f,0.f,0.f}; } \
        if (!z1) { r10 = *(const float4*)q1_; r11 = *(const float4*)(q1_ + 4); }\
        else { r10 = (float4){0.f,0.f,0.f,0.f}; r11 = (float4){0.f,0.f,0.f,0.f}; } \
    } while (0)
#define WRITEB(sl) do {                                                         \
        uint4 w0_, w1_;                                                         \
        w0_.x = pk2(r00.x, r00.y); w0_.y = pk2(r00.z, r00.w);                   \
        w0_.z = pk2(r01.x, r01.y); w0_.w = pk2(r01.z, r01.w);                   \
        w1_.x = pk2(r10.x, r10.y); w1_.y = pk2(r10.z, r10.w);                   \
        w1_.z = pk2(r11.x, r11.y); w1_.w = pk2(r11.z, r11.w);                   \
        *(uint4*)&sB[sl][oA0 + lane * 8] = w0_;                                 \
        *(uint4*)&sB[sl][oA1 + lane * 8] = w1_;                                 \
    } while (0)

    // prologue: B tile0 regs -> LDS slot0; A tiles 0,1 DMA in flight; B tile1 regs issued
    LOADB(0);
    async16(gA0, &sA[0][oA0]); async16(gA1, &sA[0][oA1]);
    async16(gA0 + 32, &sA[1][oA0]); async16(gA1 + 32, &sA[1][oA1]);
    WRITEB(0);              // compiler-inserted vmcnt wait covers B(0) loads
    LOADB(1);

    int curA = 0;
    for (int it = 0; it < nb; ++it) {
        BAR_PLAIN();                           // all waves done reading LDS (prev iter)
        if (it + 1 < nb) WRITEB((it + 1) & 1); // stage next B tile (regs -> LDS)
        if (it + 2 < nb) {
            LOADB(it + 2);                     // issue next B reg-loads (1 iter of cover)
            const int k1 = (it + 2) * 32;
            int nxt = curA + 2; if (nxt >= 3) nxt -= 3;
            async16(gA0 + k1, &sA[nxt][oA0]); async16(gA1 + k1, &sA[nxt][oA1]);
            BAR_VM8L0();                       // A(it) guaranteed by WRITEB's vmcnt(2)
        } else if (it + 1 < nb) {
            BAR_VM2L0();
        } else {
            BAR_VM0L0();
        }
        bf16x8 av[4], bv[4];
#pragma unroll
        for (int t4 = 0; t4 < 4; ++t4) av[t4] = *(const bf16x8*)&sA[curA][oa[t4]];
#pragma unroll
        for (int t4 = 0; t4 < 4; ++t4) bv[t4] = *(const bf16x8*)&sB[it & 1][ob[t4]];
#pragma unroll
        for (int mt = 0; mt < 4; ++mt)
#pragma unroll
            for (int nt = 0; nt < 4; ++nt)
                acc[mt][nt] = MFMA16(av[mt], bv[nt], acc[mt][nt]);
        if (++curA >= 3) curA = 0;
    }
#undef LOADB
#undef WRITEB

    if (mode == 4 && n0 >= 2048) {
        // V^T epilogue: transpose 128x128 tile via LDS, then coalesced 16B stores.
        __syncthreads();                       // all waves done with sA/sB
        const int ST = 136;                    // padded stride (elems)
#pragma unroll
        for (int mt = 0; mt < 4; ++mt)
#pragma unroll
            for (int nt = 0; nt < 4; ++nt)
#pragma unroll
                for (int r = 0; r < 4; ++r) {
                    int lm = wm + mt * 16 + quad * 4 + r;
                    int ln = wn + nt * 16 + li;
                    bfu* p = (ln < 90) ? (sAb + ln * ST) : (sBb + (ln - 90) * ST);
                    p[lm] = f2bf(acc[mt][nt][r]);
                }
        __syncthreads();
        bfu* C2 = (bfu*)Cv2 + (size_t)(n0 - 2048) * ldm3 + m0;
        int li16 = tid & 15, ng = tid >> 4;    // 16 groups of 16 lanes
#pragma unroll
        for (int nn = 0; nn < 8; ++nn) {
            int n = ng + nn * 16;
            const bfu* p = (n < 90) ? (sAb + n * ST) : (sBb + (n - 90) * ST);
            bf16x8 v = *(const bf16x8*)(p + li16 * 8);
            *(bf16x8*)(C2 + (size_t)n * ldm3 + li16 * 8) = v;
        }
        return;
    }

#pragma unroll
    for (int mt = 0; mt < 4; ++mt)
#pragma unroll
        for (int nt = 0; nt < 4; ++nt) {
            int row = m0 + wm + mt * 16 + quad * 4;
            int col = n0 + wn + nt * 16 + li;
            if (mode == 0) {
                float* C = (float*)Cv;
#pragma unroll
                for (int r = 0; r < 4; ++r) C[(size_t)(row + r) * N + col] = acc[mt][nt][r];
            } else if (mode == 1) {
                bfu* C = (bfu*)Cv;
#pragma unroll
                for (int r = 0; r < 4; ++r) C[(size_t)(row + r) * N + col] = f2bf(acc[mt][nt][r]);
            } else {  // mode 4, kn region
                bfu* C = (bfu*)Cv;
#pragma unroll
                for (int r = 0; r < 4; ++r) C[(size_t)(row + r) * 2048 + col] = f2bf(acc[mt][nt][r]);
            }
        }
}

__global__ __launch_bounds__(256) void gemm_multi(GemmSeg s0, GemmSeg s1) {
    __shared__ bfu sA[3][128 * 32];
    __shared__ bfu sB[2][128 * 32];
    int b = blockIdx.x;
    if (b < s0.ntiles) {
        int wg = xcd_swz(b, s0.ntiles);
        int ny = s0.ntiles / s0.nx;
        gemm_body(s0.A, s0.B0, s0.B1, s0.C, s0.C2, s0.N, s0.K, s0.ldm3, s0.mode,
                  s0.nsplit, s0.npad, s0.aidx, s0.eid, s0.bstride,
                  wg / ny, wg % ny, &sA[0][0], &sB[0][0]);
    } else {
        int lb = b - s0.ntiles;
        int wg = xcd_swz(lb, s1.ntiles);
        int ny = s1.ntiles / s1.nx;
        gemm_body(s1.A, s1.B0, s1.B1, s1.C, s1.C2, s1.N, s1.K, s1.ldm3, s1.mode,
                  s1.nsplit, s1.npad, s1.aidx, s1.eid, s1.bstride,
                  wg / ny, wg % ny, &sA[0][0], &sB[0][0]);
    }
}

// ================= elementwise / norm kernels =================
__global__ __launch_bounds__(256) void k_add_rms(const float* __restrict__ x, const float* __restrict__ skip,
                                                 const float* __restrict__ w,
                                                 float* __restrict__ x1, bfu* __restrict__ n1b) {
    int t = blockIdx.x;
    size_t base = (size_t)t * H;
    float loc[8]; float ss = 0.f;
#pragma unroll
    for (int i = 0; i < 8; ++i) {
        int c = threadIdx.x + i * 256;
        float v = x[base + c] + skip[base + c];
        loc[i] = v; ss += v * v;
        x1[base + c] = v;
    }
    float tot = blk_sum(ss);
    float r = rsqrtf(tot / (float)H + EPS);
#pragma unroll
    for (int i = 0; i < 8; ++i) {
        int c = threadIdx.x + i * 256;
        n1b[base + c] = f2bf(loc[i] * r * w[c]);
    }
}

// merged: qa_norm over qkv[:,:1536] -> qab ; ckv=rms(qkv[:,1536:2048])*w ; kpe=rope(qkv[:,2048:2112])
__global__ __launch_bounds__(256) void k_qkv_post(const bfu* __restrict__ qkv,
                                                  const float* __restrict__ qa_nw,
                                                  const float* __restrict__ kva_nw,
                                                  const float* __restrict__ sin_, const float* __restrict__ cos_,
                                                  bfu* __restrict__ qab, bfu* __restrict__ ckv,
                                                  bfu* __restrict__ kpe) {
    int t = blockIdx.x;
    const bfu* row = qkv + (size_t)t * 2176;
    float qa[6]; float ss1 = 0.f;
#pragma unroll
    for (int i = 0; i < 6; ++i) {
        float v = bf2f(row[threadIdx.x + i * 256]); qa[i] = v; ss1 += v * v;
    }
    float v0 = bf2f(row[1536 + threadIdx.x]), v1 = bf2f(row[1792 + threadIdx.x]);
    float s1 = blk_sum(ss1);
    float s2 = blk_sum(v0 * v0 + v1 * v1);
    float r1 = rsqrtf(s1 / (float)QL + EPS);
    float r2 = rsqrtf(s2 / 512.f + EPS);
#pragma unroll
    for (int i = 0; i < 6; ++i) {
        int c = threadIdx.x + i * 256;
        qab[(size_t)t * QL + c] = f2bf(qa[i] * r1 * qa_nw[c]);
    }
    ckv[(size_t)t * 512 + threadIdx.x]       = f2bf(v0 * r2 * kva_nw[threadIdx.x]);
    ckv[(size_t)t * 512 + threadIdx.x + 256] = f2bf(v1 * r2 * kva_nw[threadIdx.x + 256]);
    if (threadIdx.x < 32) {
        int p = threadIdx.x;
        float x1v = bf2f(row[2048 + 2 * p]), x2v = bf2f(row[2048 + 2 * p + 1]);
        float s = sin_[t * 32 + p], c = cos_[t * 32 + p];
        kpe[(size_t)t * 64 + 2 * p]     = f2bf(x1v * c - x2v * s);
        kpe[(size_t)t * 64 + 2 * p + 1] = f2bf(x1v * s + x2v * c);
    }
}

// ================= MFMA flash attention v2: QBLK=64 (4 waves), KVBLK=64 ================
__global__ __launch_bounds__(256) void k_flash_mfma(const bfu* __restrict__ qb,   // [T][NH][192]
                                                    const bfu* __restrict__ kn,   // [T][NH*128]
                                                    const bfu* __restrict__ kpe,  // [T][64]
                                                    const bfu* __restrict__ vt,   // [NH*128][T]
                                                    bfu* __restrict__ O,          // [T][NH*128]
                                                    const float* __restrict__ rsin,
                                                    const float* __restrict__ rcos, int T) {
    __shared__ bfu Ks[64 * 200];        // 64 K-rows x (192 + 8 pad)
    __shared__ bfu VtL[2][128 * 40];    // two 32-k planes, 80B row stride
    __shared__ bfu P[64 * 72];          // 64 q-rows x (64 + 8 pad)
    const int tid = threadIdx.x;
    const int lane = tid & 63, w = tid >> 6;           // 4 waves
    const int quad = lane >> 4, li = lane & 15;
    const int q0 = ((int)gridDim.x - 1 - (int)blockIdx.x) * 64;   // LPT order
    const int h = blockIdx.y;
    const float scale = 0.07216878364870322f;  // 1/sqrt(192)

    // Q fragments with fused interleaved RoPE on d in [128,192)
    bf16x8 qf[6];
    {
        int qrow = q0 + w * 16 + li;
        const bfu* qp = qb + ((size_t)qrow * NH + h) * DQK;
#pragma unroll
        for (int s6 = 0; s6 < 6; ++s6) {
            bf16x8 v = *(const bf16x8*)(qp + s6 * 32 + quad * 8);
            if (s6 >= 4) {
                int pb = (s6 - 4) * 16 + quad * 4;
#pragma unroll
                for (int j = 0; j < 4; ++j) {
                    float x1 = bf2f((bfu)v[2 * j]), x2 = bf2f((bfu)v[2 * j + 1]);
                    float s = rsin[qrow * 32 + pb + j], c = rcos[qrow * 32 + pb + j];
                    v[2 * j]     = (short)f2bf(x1 * c - x2 * s);
                    v[2 * j + 1] = (short)f2bf(x1 * s + x2 * c);
                }
            }
            qf[s6] = v;
        }
    }
    f32x4 accO[8];
#pragma unroll
    for (int i = 0; i < 8; ++i) accO[i] = (f32x4){0.f, 0.f, 0.f, 0.f};
    float lrow[4] = {0.f, 0.f, 0.f, 0.f};

    // staging descriptors (256 threads)
    int kr[6], kg[6];
#pragma unroll
    for (int it = 0; it < 6; ++it) { int G = tid + it * 256; kr[it] = G / 24; kg[it] = G % 24; }
    int vn[4], vgl[4], vkc[4];
#pragma unroll
    for (int it = 0; it < 4; ++it) {
        int idx = tid + it * 256; vn[it] = idx >> 3; vgl[it] = idx & 7;
        vkc[it] = (vgl[it] & 4) | ((vgl[it] & 3) ^ ((vn[it] >> 1) & 3));
    }
    bf16x8 kreg[6], vreg[4];
#pragma unroll
    for (int it = 0; it < 6; ++it)
        kreg[it] = (kg[it] < 16) ? *(const bf16x8*)(kn + (size_t)kr[it] * (NH * 128) + h * 128 + kg[it] * 8)
                                 : *(const bf16x8*)(kpe + (size_t)kr[it] * 64 + (kg[it] - 16) * 8);
#pragma unroll
    for (int it = 0; it < 4; ++it)
        vreg[it] = *(const bf16x8*)(vt + (size_t)(h * 128 + vn[it]) * T + vkc[it] * 8);

    const int fgv = (quad ^ ((li >> 1) & 3)) * 8;
    const int kend = q0 + 64;
    for (int k0 = 0; k0 < kend; k0 += 64) {
        BAR_PLAIN();                            // all waves done reading LDS (prev iter)
#pragma unroll
        for (int it = 0; it < 6; ++it) *(bf16x8*)(Ks + kr[it] * 200 + kg[it] * 8) = kreg[it];
#pragma unroll
        for (int it = 0; it < 4; ++it)
            *(bf16x8*)(VtL[vgl[it] >> 2] + vn[it] * 40 + (vgl[it] & 3) * 8) = vreg[it];
        if (k0 + 64 < kend) {                   // prefetch next tile into regs (stays in flight)
            int k1 = k0 + 64;
#pragma unroll
            for (int it = 0; it < 6; ++it)
                kreg[it] = (kg[it] < 16) ? *(const bf16x8*)(kn + (size_t)(k1 + kr[it]) * (NH * 128) + h * 128 + kg[it] * 8)
                                         : *(const bf16x8*)(kpe + (size_t)(k1 + kr[it]) * 64 + (kg[it] - 16) * 8);
#pragma unroll
            for (int it = 0; it < 4; ++it)
                vreg[it] = *(const bf16x8*)(vt + (size_t)(h * 128 + vn[it]) * T + k1 + vkc[it] * 8);
        }
        BAR_LGKM0();                            // LDS tile visible; global prefetch NOT drained
        // S = Q K^T : 4 column sub-tiles of 16
        f32x4 s[4];
#pragma unroll
        for (int ct = 0; ct < 4; ++ct) {
            f32x4 a = (f32x4){0.f, 0.f, 0.f, 0.f};
#pragma unroll
            for (int s6 = 0; s6 < 6; ++s6) {
                bf16x8 kf = *(const bf16x8*)(Ks + (ct * 16 + li) * 200 + s6 * 32 + quad * 8);
                a = MFMA16(qf[s6], kf, a);
            }
            s[ct] = a;
        }
#pragma unroll
        for (int ct = 0; ct < 4; ++ct)
#pragma unroll
            for (int r = 0; r < 4; ++r) {
                int row = q0 + w * 16 + quad * 4 + r;
                float p = (k0 + ct * 16 + li <= row) ? __expf(s[ct][r] * scale) : 0.f;
                s[ct][r] = p;
                lrow[r] += p;
            }
        // P round trip: C-layout -> A-layout (wave-private rows; LDS per-wave in-order)
#pragma unroll
        for (int ct = 0; ct < 4; ++ct)
#pragma unroll
            for (int r = 0; r < 4; ++r)
                P[(w * 16 + quad * 4 + r) * 72 + ct * 16 + li] = f2bf(s[ct][r]);
        bf16x8 pf[2];
#pragma unroll
        for (int ks = 0; ks < 2; ++ks)
            pf[ks] = *(const bf16x8*)(P + (w * 16 + li) * 72 + ks * 32 + quad * 8);
#pragma unroll
        for (int v8 = 0; v8 < 8; ++v8)
#pragma unroll
            for (int ks = 0; ks < 2; ++ks) {
                bf16x8 vf = *(const bf16x8*)(VtL[ks] + (v8 * 16 + li) * 40 + fgv);
                accO[v8] = MFMA16(pf[ks], vf, accO[v8]);
            }
    }
#pragma unroll
    for (int r = 0; r < 4; ++r) {
        float l = lrow[r];
        l += __shfl_xor(l, 1); l += __shfl_xor(l, 2);
        l += __shfl_xor(l, 4); l += __shfl_xor(l, 8);
        lrow[r] = 1.0f / l;
    }
#pragma unroll
    for (int v8 = 0; v8 < 8; ++v8)
#pragma unroll
        for (int r = 0; r < 4; ++r) {
            float val = accO[v8][r] * lrow[r];
            O[(size_t)(q0 + w * 16 + quad * 4 + r) * (NH * 128) + h * 128 + v8 * 16 + li] = f2bf(val);
        }
}

// x2 = x1 + attn -> d_out ; n2_bf ; FUSED gate: top-2 over 8 experts (single-barrier reduce)
__global__ __launch_bounds__(256) void k_x2_n2(const float* __restrict__ x1, const bfu* __restrict__ attn,
                                               const float* __restrict__ ln2w, float* __restrict__ outx2,
                                               bfu* __restrict__ n2b, const float* __restrict__ gw,
                                               int* __restrict__ eidx, float* __restrict__ wts,
                                               int* __restrict__ cnt) {
    int t = blockIdx.x;
    size_t base = (size_t)t * H;
    float loc[8]; float ss = 0.f;
#pragma unroll
    for (int i = 0; i < 8; ++i) {
        int c = threadIdx.x + i * 256;
        float vv = x1[base + c] + bf2f(attn[base + c]);
        loc[i] = vv; ss += vv * vv;
        outx2[base + c] = vv;
    }
    float tot = blk_sum(ss);
    float r = rsqrtf(tot / (float)H + EPS);
    float pe[NE] = {0.f, 0.f, 0.f, 0.f, 0.f, 0.f, 0.f, 0.f};
#pragma unroll
    for (int i = 0; i < 8; ++i) {
        int c = threadIdx.x + i * 256;
        float nv = loc[i] * r * ln2w[c];
        n2b[base + c] = f2bf(nv);
#pragma unroll
        for (int e = 0; e < NE; ++e) pe[e] += nv * gw[e * H + c];
    }
    __shared__ float sred[4][NE];
    int lane = threadIdx.x & 63, wv = threadIdx.x >> 6;
#pragma unroll
    for (int e = 0; e < NE; ++e) {
        float v = pe[e];
        for (int o = 32; o > 0; o >>= 1) v += __shfl_down(v, o, 64);
        if (lane == 0) sred[wv][e] = v;
    }
    __syncthreads();
    if (threadIdx.x == 0) {
        float logits[NE];
        float m = -1e30f;
        for (int e = 0; e < NE; ++e) {
            logits[e] = sred[0][e] + sred[1][e] + sred[2][e] + sred[3][e];
            m = fmaxf(m, logits[e]);
        }
        float p[NE];
        for (int e = 0; e < NE; ++e) p[e] = __expf(logits[e] - m);
        int i1 = 0;
        for (int e = 1; e < NE; ++e) if (p[e] > p[i1]) i1 = e;
        int i2 = -1;
        for (int e = 0; e < NE; ++e) if (e != i1 && (i2 < 0 || p[e] > p[i2])) i2 = e;
        float denom = p[i1] + p[i2];
        eidx[t * 2] = i1; eidx[t * 2 + 1] = i2;
        wts[t * 2] = p[i1] / denom; wts[t * 2 + 1] = p[i2] / denom;
        atomicAdd(&cnt[i1], 1); atomicAdd(&cnt[i2], 1);
    }
}

// ================= MoE routing =================
__global__ __launch_bounds__(256) void k_moe_init(int* __restrict__ cnt, int* __restrict__ slot,
                                                  int* __restrict__ eid, int* __restrict__ idx,
                                                  float* __restrict__ aw) {
    int tid = threadIdx.x;
    if (tid < NE) { cnt[tid] = 0; slot[tid] = 0; }
    if (tid < 40) eid[tid] = 0;
    for (int i = tid; i < MAXA; i += 256) { idx[i] = 0; aw[i] = 0.f; }
}

__global__ __launch_bounds__(64) void k_moe_scan(const int* __restrict__ cnt, int* __restrict__ base,
                                                 int* __restrict__ eid) {
    if (threadIdx.x == 0) {
        int off = 0;
        for (int e = 0; e < NE; ++e) {
            base[e] = off;
            int nb = (cnt[e] + 127) >> 7;
            for (int j = 0; j < nb; ++j) eid[(off >> 7) + j] = e;
            off += nb << 7;
        }
    }
}

__global__ __launch_bounds__(256) void k_moe_scatter(const int* __restrict__ eidx, const float* __restrict__ wts,
                                                     const int* __restrict__ base, int* __restrict__ slot,
                                                     int* __restrict__ idx, float* __restrict__ aw,
                                                     int* __restrict__ posmap) {
    int t = blockIdx.x * 256 + threadIdx.x;
#pragma unroll
    for (int j = 0; j < 2; ++j) {
        int e = eidx[t * 2 + j];
        int p = base[e] + atomicAdd(&slot[e], 1);
        idx[p] = t; aw[p] = wts[t * 2 + j]; posmap[t * 2 + j] = p;
    }
}

// merged silu: blocks [0,T) = shared expert rows; blocks [T, T+MAXA) = sparse MoE rows
__global__ __launch_bounds__(256) void k_silu_both(const bfu* __restrict__ hsh, bfu* __restrict__ gsh,
                                                   const bfu* __restrict__ hsp, const float* __restrict__ aw,
                                                   bfu* __restrict__ gsp, int T) {
    int b = blockIdx.x;
    if (b < T) {
        const bfu* row = hsh + (size_t)b * 2048;
        bfu* grow = gsh + (size_t)b * 1024;
#pragma unroll
        for (int j = 0; j < 4; ++j) {
            int i = threadIdx.x + j * 256;
            float a = bf2f(row[i]), bb = bf2f(row[1024 + i]);
            grow[i] = f2bf(a / (1.0f + __expf(-a)) * bb);
        }
    } else {
        int row = b - T;
        float we = aw[row];
        const bfu* hr = hsp + (size_t)row * 1024;
        bfu* gr = gsp + (size_t)row * 512;
#pragma unroll
        for (int j = 0; j < 2; ++j) {
            int i = threadIdx.x + j * 256;
            float a = bf2f(hr[i]), bb = bf2f(hr[512 + i]);
            gr[i] = f2bf(we * a / (1.0f + __expf(-a)) * bb);
        }
    }
}

__global__ __launch_bounds__(256) void k_ffn_out(const float* __restrict__ routed, const bfu* __restrict__ dsp,
                                                 const int* __restrict__ posmap, float* __restrict__ out,
                                                 size_t TH) {
    int t = blockIdx.x;
    int p1 = posmap[t * 2], p2 = posmap[t * 2 + 1];
    const bfu* d1 = dsp + (size_t)p1 * H;
    const bfu* d2 = dsp + (size_t)p2 * H;
#pragma unroll
    for (int j = 0; j < 8; ++j) {
        int c = threadIdx.x + j * 256;
        out[TH + (size_t)t * H + c] = routed[(size_t)t * H + c] + bf2f(d1[c]) + bf2f(d2[c]);
    }
}

static inline GemmSeg mk_seg(const bfu* A, const float* B0, const float* B1, void* C, void* C2,
                             const int* aidx, const int* eid, long bstride,
                             int N, int K, int ldm3, int mode, int nx, int ny,
                             int nsplit, int npad) {
    GemmSeg s;
    s.A = A; s.B0 = B0; s.B1 = B1; s.C = C; s.C2 = C2; s.aidx = aidx; s.eid = eid;
    s.bstride = bstride; s.N = N; s.K = K; s.ldm3 = ldm3; s.mode = mode;
    s.nx = nx; s.ntiles = nx * ny; s.nsplit = nsplit; s.npad = npad;
    return s;
}

extern "C" void kernel_launch(void* const* d_in, const int* in_sizes, int n_in,
                              void* d_out, int out_size, void* d_ws, size_t ws_size,
                              hipStream_t stream) {
    const float* x      = (const float*)d_in[0];
    const float* skip   = (const float*)d_in[1];
    const float* rsin   = (const float*)d_in[2];
    const float* rcos   = (const float*)d_in[3];
    const float* ln1w   = (const float*)d_in[4];
    const float* ln2w   = (const float*)d_in[5];
    const float* w_qa   = (const float*)d_in[6];
    const float* qa_nw  = (const float*)d_in[7];
    const float* w_qb   = (const float*)d_in[8];
    const float* w_kva  = (const float*)d_in[9];
    const float* kva_nw = (const float*)d_in[10];
    const float* w_kb   = (const float*)d_in[11];
    const float* w_vb   = (const float*)d_in[12];
    const float* w_o    = (const float*)d_in[13];
    const float* gate_w = (const float*)d_in[14];
    const float* mup    = (const float*)d_in[15];
    const float* mdown  = (const float*)d_in[16];
    const float* shup   = (const float*)d_in[17];
    const float* shdown = (const float*)d_in[18];

    const int T = in_sizes[0] / H;   // 2048

    // ---- activation arena only (weights consumed f32-direct by GEMMs) ----
    char* AB = (char*)d_ws;
    float* x1f    = (float*)(AB + 0);           // A0 16MB: x1 (dead after x2_n2)
    float* routed = (float*)(AB + 0);           //   A0 reuse: shared-expert down out
    bfu*   n1b    = (bfu*)(AB + 16777216);      // A1 8MB: n1 -> n2 bf16
    bfu*   qkvb   = (bfu*)(AB + 25165824);      // A2 10.49MB: qkv bf16 [T][2176] (8.9MB)
    bfu*   knb    = (bfu*)(AB + 25165824);      //   A2 reuse: k_nope (8MB)
    bfu*   hsp    = (bfu*)(AB + 25165824);      //   A2 reuse: MoE up out (10.49MB)
    bfu*   qab    = (bfu*)(AB + 35651584);      // A3 6.29MB: qa normed
    bfu*   gsp    = (bfu*)(AB + 35651584);      //   A3 reuse: MoE silu out (5.24MB)
    bfu*   qbb    = (bfu*)(AB + 41943040);      // A4 12.58MB: q bf16
    bfu*   attnb  = (bfu*)(AB + 41943040);      //   A4 reuse: attn bf16 (8MB)
    bfu*   ckvb   = (bfu*)(AB + 54525952);      // A5 2.10MB
    bfu*   kpeb   = (bfu*)(AB + 56623104);      // A6 0.26MB
    char*  G      = AB + 56885248;              // gate/routing arrays (128KB)
    int*   eidx   = (int*)(G);
    float* wts    = (float*)(G + 16384);
    int*   posmap = (int*)(G + 32768);
    int*   midx   = (int*)(G + 49152);
    float* maw    = (float*)(G + 69632);
    int*   mcnt   = (int*)(G + 90112);
    int*   mbase  = (int*)(G + 90112 + 64);
    int*   mslot  = (int*)(G + 90112 + 128);
    int*   meid   = (int*)(G + 90112 + 192);
    bfu*   ob     = (bfu*)(AB + 57016320);      // A7 8.39MB: attention O
    bfu*   gsb    = (bfu*)(AB + 57016320);      //   A7 reuse: shared silu out
    bfu*   vtb    = (bfu*)(AB + 65404928);      // A8 20.97MB: V^T (8.39MB)
    bfu*   hsb    = (bfu*)(AB + 65404928);      //   A8 reuse: shared up out (8.39MB)
    bfu*   dsp    = (bfu*)(AB + 65404928);      //   A8 reuse: MoE down out (20.97MB)
    const size_t REQ = 86376448;                // ~86.4 MB
    if (ws_size < REQ) return;

    // 1) x1, n1
    k_add_rms<<<T, 256, 0, stream>>>(x, skip, ln1w, x1f, n1b);
    // 2) merged qa+kva GEMM: qkv = n1 @ [w_qa; w_kva]^T  (N=2176; rows>=2112 zero-pad)
    {
        GemmSeg s = mk_seg(n1b, w_qa, w_kva, qkvb, nullptr, nullptr, nullptr, 0,
                           2176, H, 0, 1, 2176 / 128, T / 128, 1536, 2112);
        gemm_multi<<<s.ntiles, 256, 0, stream>>>(s, s);
    }
    k_qkv_post<<<T, 256, 0, stream>>>(qkvb, qa_nw, kva_nw, rsin, rcos, qab, ckvb, kpeb);
    // 3+4) MERGED: q = qa @ w_qb^T  ||  kbv: kn normal + V^T transposed
    {
        GemmSeg sq = mk_seg(qab, w_qb, w_qb, qbb, nullptr, nullptr, nullptr, 0,
                            NH * DQK, QL, 0, 1, (NH * DQK) / 128, T / 128, NH * DQK, NH * DQK);
        GemmSeg sk = mk_seg(ckvb, w_kb, w_vb, knb, vtb, nullptr, nullptr, 0,
                            4096, KVL, T, 4, 4096 / 128, T / 128, 2048, 4096);
        gemm_multi<<<sq.ntiles + sk.ntiles, 256, 0, stream>>>(sq, sk);
    }
    // 5) flash attention v2 -> O bf16 (64-row q blocks, 64-row KV tiles)
    k_flash_mfma<<<dim3(T / 64, NH), 256, 0, stream>>>(qbb, knb, kpeb, vtb, ob, rsin, rcos, T);
    // 6) attn = O @ w_o^T
    {
        GemmSeg s = mk_seg(ob, w_o, w_o, attnb, nullptr, nullptr, nullptr, 0,
                           H, NH * VD, 0, 1, H / 128, T / 128, H, H);
        gemm_multi<<<s.ntiles, 256, 0, stream>>>(s, s);
    }
    // 7) routing init + x2/n2/gate fused
    k_moe_init<<<1, 256, 0, stream>>>(mcnt, mslot, meid, midx, maw);
    k_x2_n2<<<T, 256, 0, stream>>>(x1f, attnb, ln2w, (float*)d_out, n1b, gate_w, eidx, wts, mcnt);
    k_moe_scan<<<1, 64, 0, stream>>>(mcnt, mbase, meid);
    k_moe_scatter<<<T / 256, 256, 0, stream>>>(eidx, wts, mbase, mslot, midx, maw, posmap);
    // 8+9a) MERGED: shared-up  ||  sparse MoE up (both read n2)
    {
        GemmSeg ssh = mk_seg(n1b, shup, shup, hsb, nullptr, nullptr, nullptr, 0,
                             2048, H, 0, 1, 2048 / 128, T / 128, 2048, 2048);
        GemmSeg smo = mk_seg(n1b, mup, mup, hsp, nullptr, midx, meid, (long)1024 * H,
                             1024, H, 0, 1, 1024 / 128, MAXA / 128, 1024, 1024);
        gemm_multi<<<ssh.ntiles + smo.ntiles, 256, 0, stream>>>(ssh, smo);
    }
    // silu (shared + sparse in one dispatch)
    k_silu_both<<<T + MAXA, 256, 0, stream>>>(hsb, gsb, hsp, maw, gsp, T);
    // 8b+9b) MERGED: shared-down (f32)  ||  sparse MoE down
    {
        GemmSeg ssd = mk_seg(gsb, shdown, shdown, routed, nullptr, nullptr, nullptr, 0,
                             H, SHI, 0, 0, H / 128, T / 128, H, H);
        GemmSeg smd = mk_seg(gsp, mdown, mdown, dsp, nullptr, nullptr, meid, (long)H * MI_D,
                             H, MI_D, 0, 1, H / 128, MAXA / 128, H, H);
        gemm_multi<<<ssd.ntiles + smd.ntiles, 256, 0, stream>>>(ssd, smd);
    }
    // 10) ffn writeout
    k_ffn_out<<<T, 256, 0, stream>>>(routed, dsp, posmap, (float*)d_out, (size_t)T * H);
}

// Round 6
// 610.029 us; speedup vs baseline: 1.1996x; 1.1996x over previous
//
#include <hip/hip_runtime.h>
#include <hip/hip_bf16.h>

// ---- problem constants ----
#define H 2048
#define NH 16
#define NOPE 128
#define ROPE_D 64
#define DQK 192      // NOPE + ROPE
#define VD 128
#define QL 1536
#define KVL 512
#define NE 8
#define MI_D 512
#define SHI 1024     // SH_I = 2*MI
#define EPS 1e-6f
#define MAXA 5120    // max padded MoE assignments

typedef unsigned short bfu;   // raw bf16 bits
typedef short bf16x8 __attribute__((ext_vector_type(8)));
typedef float f32x4 __attribute__((ext_vector_type(4)));

#define MFMA16(a, b, c) __builtin_amdgcn_mfma_f32_16x16x32_bf16(a, b, c, 0, 0, 0)

// raw barriers: avoid the compiler's s_waitcnt vmcnt(0) drain before s_barrier
#define BAR_PLAIN()   asm volatile("s_barrier" ::: "memory")
#define BAR_LGKM0()   asm volatile("s_waitcnt lgkmcnt(0)\n\ts_barrier" ::: "memory")
#define BAR_VM4()     asm volatile("s_waitcnt vmcnt(4)\n\ts_barrier" ::: "memory")
#define BAR_VM0()     asm volatile("s_waitcnt vmcnt(0)\n\ts_barrier" ::: "memory")

__device__ __forceinline__ float bf2f(bfu u) {
    union { unsigned int i; float f; } w; w.i = ((unsigned int)u) << 16; return w.f;
}
__device__ __forceinline__ bfu f2bf(float f) {
    union { float f; unsigned int i; } u; u.f = f;
    return (bfu)((u.i + 0x7fffu + ((u.i >> 16) & 1u)) >> 16);
}

__device__ __forceinline__ void async16(const bfu* g, bfu* l) {
    __builtin_amdgcn_global_load_lds((const __attribute__((address_space(1))) void*)g,
                                     (__attribute__((address_space(3))) void*)l, 16, 0, 0);
}

// block-wide sum over 256 threads (4 waves of 64)
__device__ __forceinline__ float blk_sum(float v) {
    __shared__ float sb[4];
    for (int o = 32; o > 0; o >>= 1) v += __shfl_down(v, o, 64);
    int lane = threadIdx.x & 63, w = threadIdx.x >> 6;
    __syncthreads();
    if (lane == 0) sb[w] = v;
    __syncthreads();
    return sb[0] + sb[1] + sb[2] + sb[3];
}

// ================= MFMA GEMM, 3-stage ring: C[M,N] = A[M,K]bf16 @ W[N,K]^T bf16 ========
// 128x128 tile, BK=32, 256 threads. One RAW barrier per K-iter with s_waitcnt vmcnt(4).
// mode 0: f32 store; 1: bf16 store; 4: split (n0<2048 -> bf16 C ld 2048, else V^T to C2).
struct GemmSeg {
    const bfu* A; const bfu* B; void* C; void* C2;
    const int* aidx; const int* eid;
    long bstride;
    int N, K, ldm3, mode, nx, ntiles;
};

// weight cast work descriptor (granule = 16 elements), runs as tail segment of a
// gemm_multi dispatch: casts weights needed only by LATER dispatches, so the cast
// latency hides under this dispatch's GEMM compute (stream order guarantees visibility).
struct CastArgs {
    const float* s[10];
    bfu* d[10];
    unsigned start[11];   // prefix sums in 16-element granules; start[10] = total
    int pad[10];          // 1 = kva-style zero-pad rows >= 576 (stride 2048)
};

__device__ __forceinline__ void gemm_body(const bfu* __restrict__ A, const bfu* __restrict__ B,
                                          void* __restrict__ Cv, void* __restrict__ Cv2,
                                          int N, int K, int ldm3, int mode,
                                          const int* __restrict__ aidx,
                                          const int* __restrict__ eid, long bstride,
                                          int bx, int by,
                                          bfu* sAb, bfu* sBb) {
    bfu (*sA)[128 * 32] = (bfu (*)[128 * 32])sAb;
    bfu (*sB)[128 * 32] = (bfu (*)[128 * 32])sBb;
    const int tid = threadIdx.x;
    const int lane = tid & 63, w = tid >> 6;
    const int quad = lane >> 4, li = lane & 15;
    const int m0 = by * 128, n0 = bx * 128;
    const bfu* Bp = B + (eid ? (size_t)eid[by] * bstride : 0);

    const int l4 = lane >> 2;              // row within 16
    const int lg = lane & 3;               // lds granule
    const int kc = lg ^ ((lane >> 3) & 3); // swizzled source chunk
    int r0 = m0 + w * 32 + l4, r1 = r0 + 16;
    if (aidx) { r0 = aidx[r0]; r1 = aidx[r1]; }
    const bfu* gA0 = A + (size_t)r0 * K + kc * 8;
    const bfu* gA1 = A + (size_t)r1 * K + kc * 8;
    const bfu* gB0 = Bp + (size_t)(n0 + w * 32 + l4) * K + kc * 8;
    const bfu* gB1 = gB0 + (size_t)16 * K;
    const int oA0 = (w * 32) * 32, oA1 = (w * 32 + 16) * 32;

    const int wm = (w >> 1) * 64, wn = (w & 1) * 64;
    const int fg = (quad ^ ((li >> 1) & 3)) * 8;
    int oa[4], ob[4];
#pragma unroll
    for (int t4 = 0; t4 < 4; ++t4) {
        oa[t4] = (wm + t4 * 16 + li) * 32 + fg;
        ob[t4] = (wn + t4 * 16 + li) * 32 + fg;
    }
    f32x4 acc[4][4];
#pragma unroll
    for (int i = 0; i < 4; ++i)
#pragma unroll
        for (int j = 0; j < 4; ++j) acc[i][j] = (f32x4){0.f, 0.f, 0.f, 0.f};

    const int nb = K / 32;
    // prologue: tiles 0 and 1 in flight (8 outstanding loads/thread)
    async16(gA0, &sA[0][oA0]); async16(gA1, &sA[0][oA1]);
    async16(gB0, &sB[0][oA0]); async16(gB1, &sB[0][oA1]);
    async16(gA0 + 32, &sA[1][oA0]); async16(gA1 + 32, &sA[1][oA1]);
    async16(gB0 + 32, &sB[1][oA0]); async16(gB1 + 32, &sB[1][oA1]);

    int cur = 0;
    for (int it = 0; it < nb; ++it) {
        if (it < nb - 1) { BAR_VM4(); } else { BAR_VM0(); }   // tile `it` resident in LDS
        bf16x8 av[4], bv[4];
#pragma unroll
        for (int t4 = 0; t4 < 4; ++t4) av[t4] = *(const bf16x8*)&sA[cur][oa[t4]];
#pragma unroll
        for (int t4 = 0; t4 < 4; ++t4) bv[t4] = *(const bf16x8*)&sB[cur][ob[t4]];
        if (it + 2 < nb) {
            const int k1 = (it + 2) * 32;
            int nxt = cur + 2; if (nxt >= 3) nxt -= 3;
            async16(gA0 + k1, &sA[nxt][oA0]); async16(gA1 + k1, &sA[nxt][oA1]);
            async16(gB0 + k1, &sB[nxt][oA0]); async16(gB1 + k1, &sB[nxt][oA1]);
        }
#pragma unroll
        for (int mt = 0; mt < 4; ++mt)
#pragma unroll
            for (int nt = 0; nt < 4; ++nt)
                acc[mt][nt] = MFMA16(av[mt], bv[nt], acc[mt][nt]);
        if (++cur >= 3) cur = 0;
    }

#pragma unroll
    for (int mt = 0; mt < 4; ++mt)
#pragma unroll
        for (int nt = 0; nt < 4; ++nt) {
            int row = m0 + wm + mt * 16 + quad * 4;
            int col = n0 + wn + nt * 16 + li;
            if (mode == 0) {
                float* C = (float*)Cv;
#pragma unroll
                for (int r = 0; r < 4; ++r) C[(size_t)(row + r) * N + col] = acc[mt][nt][r];
            } else if (mode == 1) {
                bfu* C = (bfu*)Cv;
#pragma unroll
                for (int r = 0; r < 4; ++r) C[(size_t)(row + r) * N + col] = f2bf(acc[mt][nt][r]);
            } else {  // mode 4: kn normal (col<2048) or V^T transposed
                if (n0 < 2048) {
                    bfu* C = (bfu*)Cv;
#pragma unroll
                    for (int r = 0; r < 4; ++r) C[(size_t)(row + r) * 2048 + col] = f2bf(acc[mt][nt][r]);
                } else {
                    bfu* C2 = (bfu*)Cv2;
                    ushort4 u;
                    u.x = f2bf(acc[mt][nt][0]); u.y = f2bf(acc[mt][nt][1]);
                    u.z = f2bf(acc[mt][nt][2]); u.w = f2bf(acc[mt][nt][3]);
                    *(ushort4*)(C2 + (size_t)(col - 2048) * ldm3 + row) = u;
                }
            }
        }
}

// two GEMM segments + cast tail segment in one dispatch
__global__ __launch_bounds__(256) void gemm_multi(GemmSeg s0, GemmSeg s1, CastArgs ca) {
    __shared__ bfu sA[3][128 * 32];
    __shared__ bfu sB[3][128 * 32];
    int b = blockIdx.x;
    if (b < s0.ntiles) {
        gemm_body(s0.A, s0.B, s0.C, s0.C2, s0.N, s0.K, s0.ldm3, s0.mode,
                  s0.aidx, s0.eid, s0.bstride, b % s0.nx, b / s0.nx, &sA[0][0], &sB[0][0]);
    } else if (b < s0.ntiles + s1.ntiles) {
        int lb = b - s0.ntiles;
        gemm_body(s1.A, s1.B, s1.C, s1.C2, s1.N, s1.K, s1.ldm3, s1.mode,
                  s1.aidx, s1.eid, s1.bstride, lb % s1.nx, lb / s1.nx, &sA[0][0], &sB[0][0]);
    } else {
        unsigned g = (unsigned)(b - s0.ntiles - s1.ntiles) * 256 + threadIdx.x;
        if (g >= ca.start[10]) return;
        int id = 0;
#pragma unroll
        for (int i = 1; i < 10; ++i) if (g >= ca.start[i]) id = i;
        size_t i16 = (size_t)(g - ca.start[id]) * 16;
        ushort4 u[4] = {};
        if (!ca.pad[id] || (i16 >> 11) < 576) {
            const float* s = ca.s[id];
#pragma unroll
            for (int j = 0; j < 4; ++j) {
                float4 xv = *(const float4*)(s + i16 + j * 4);
                u[j].x = f2bf(xv.x); u[j].y = f2bf(xv.y); u[j].z = f2bf(xv.z); u[j].w = f2bf(xv.w);
            }
        }
        bfu* d = ca.d[id];
#pragma unroll
        for (int j = 0; j < 4; ++j) *(ushort4*)(d + i16 + j * 4) = u[j];
    }
}

// ================= elementwise / norm kernels =================
__global__ __launch_bounds__(256) void k_add_rms(const float* __restrict__ x, const float* __restrict__ skip,
                                                 const float* __restrict__ w,
                                                 float* __restrict__ x1, bfu* __restrict__ n1b) {
    int t = blockIdx.x;
    size_t base = (size_t)t * H;
    float loc[8]; float ss = 0.f;
#pragma unroll
    for (int i = 0; i < 8; ++i) {
        int c = threadIdx.x + i * 256;
        float v = x[base + c] + skip[base + c];
        loc[i] = v; ss += v * v;
        x1[base + c] = v;
    }
    float tot = blk_sum(ss);
    float r = rsqrtf(tot / (float)H + EPS);
#pragma unroll
    for (int i = 0; i < 8; ++i) {
        int c = threadIdx.x + i * 256;
        n1b[base + c] = f2bf(loc[i] * r * w[c]);
    }
}

// merged: qa_norm over qkv[:,:1536] -> qab ; ckv=rms(qkv[:,1536:2048])*w ; kpe=rope(qkv[:,2048:2112])
__global__ __launch_bounds__(256) void k_qkv_post(const bfu* __restrict__ qkv,
                                                  const float* __restrict__ qa_nw,
                                                  const float* __restrict__ kva_nw,
                                                  const float* __restrict__ sin_, const float* __restrict__ cos_,
                                                  bfu* __restrict__ qab, bfu* __restrict__ ckv,
                                                  bfu* __restrict__ kpe) {
    int t = blockIdx.x;
    const bfu* row = qkv + (size_t)t * 2176;
    float qa[6]; float ss1 = 0.f;
#pragma unroll
    for (int i = 0; i < 6; ++i) {
        float v = bf2f(row[threadIdx.x + i * 256]); qa[i] = v; ss1 += v * v;
    }
    float v0 = bf2f(row[1536 + threadIdx.x]), v1 = bf2f(row[1792 + threadIdx.x]);
    float s1 = blk_sum(ss1);
    float s2 = blk_sum(v0 * v0 + v1 * v1);
    float r1 = rsqrtf(s1 / (float)QL + EPS);
    float r2 = rsqrtf(s2 / 512.f + EPS);
#pragma unroll
    for (int i = 0; i < 6; ++i) {
        int c = threadIdx.x + i * 256;
        qab[(size_t)t * QL + c] = f2bf(qa[i] * r1 * qa_nw[c]);
    }
    ckv[(size_t)t * 512 + threadIdx.x]       = f2bf(v0 * r2 * kva_nw[threadIdx.x]);
    ckv[(size_t)t * 512 + threadIdx.x + 256] = f2bf(v1 * r2 * kva_nw[threadIdx.x + 256]);
    if (threadIdx.x < 32) {
        int p = threadIdx.x;
        float x1v = bf2f(row[2048 + 2 * p]), x2v = bf2f(row[2048 + 2 * p + 1]);
        float s = sin_[t * 32 + p], c = cos_[t * 32 + p];
        kpe[(size_t)t * 64 + 2 * p]     = f2bf(x1v * c - x2v * s);
        kpe[(size_t)t * 64 + 2 * p + 1] = f2bf(x1v * s + x2v * c);
    }
}

// ================= MFMA flash attention v2: QBLK=64 (4 waves), KVBLK=64 ================
// m=0 softmax (scores bounded; softmax shift-invariant -> exact).
__global__ __launch_bounds__(256) void k_flash_mfma(const bfu* __restrict__ qb,   // [T][NH][192]
                                                    const bfu* __restrict__ kn,   // [T][NH*128]
                                                    const bfu* __restrict__ kpe,  // [T][64]
                                                    const bfu* __restrict__ vt,   // [NH*128][T]
                                                    bfu* __restrict__ O,          // [T][NH*128]
                                                    const float* __restrict__ rsin,
                                                    const float* __restrict__ rcos, int T) {
    __shared__ bfu Ks[64 * 200];        // 64 K-rows x (192 + 8 pad)
    __shared__ bfu VtL[2][128 * 32];    // two 32-k planes, 64B row stride
    __shared__ bfu P[64 * 72];          // 64 q-rows x (64 + 8 pad)
    const int tid = threadIdx.x;
    const int lane = tid & 63, w = tid >> 6;           // 4 waves
    const int quad = lane >> 4, li = lane & 15;
    const int q0 = ((int)gridDim.x - 1 - (int)blockIdx.x) * 64;   // LPT order
    const int h = blockIdx.y;
    const float scale = 0.07216878364870322f;  // 1/sqrt(192)

    // Q fragments with fused interleaved RoPE on d in [128,192)
    bf16x8 qf[6];
    {
        int qrow = q0 + w * 16 + li;
        const bfu* qp = qb + ((size_t)qrow * NH + h) * DQK;
#pragma unroll
        for (int s6 = 0; s6 < 6; ++s6) {
            bf16x8 v = *(const bf16x8*)(qp + s6 * 32 + quad * 8);
            if (s6 >= 4) {
                int pb = (s6 - 4) * 16 + quad * 4;
#pragma unroll
                for (int j = 0; j < 4; ++j) {
                    float x1 = bf2f((bfu)v[2 * j]), x2 = bf2f((bfu)v[2 * j + 1]);
                    float s = rsin[qrow * 32 + pb + j], c = rcos[qrow * 32 + pb + j];
                    v[2 * j]     = (short)f2bf(x1 * c - x2 * s);
                    v[2 * j + 1] = (short)f2bf(x1 * s + x2 * c);
                }
            }
            qf[s6] = v;
        }
    }
    f32x4 accO[8];
#pragma unroll
    for (int i = 0; i < 8; ++i) accO[i] = (f32x4){0.f, 0.f, 0.f, 0.f};
    float lrow[4] = {0.f, 0.f, 0.f, 0.f};

    // staging descriptors (256 threads)
    int kr[6], kg[6];
#pragma unroll
    for (int it = 0; it < 6; ++it) { int G = tid + it * 256; kr[it] = G / 24; kg[it] = G % 24; }
    int vn[4], vgl[4], vkc[4];
#pragma unroll
    for (int it = 0; it < 4; ++it) {
        int idx = tid + it * 256; vn[it] = idx >> 3; vgl[it] = idx & 7;
        vkc[it] = (vgl[it] & 4) | ((vgl[it] & 3) ^ ((vn[it] >> 1) & 3));
    }
    bf16x8 kreg[6], vreg[4];
#pragma unroll
    for (int it = 0; it < 6; ++it)
        kreg[it] = (kg[it] < 16) ? *(const bf16x8*)(kn + (size_t)kr[it] * (NH * 128) + h * 128 + kg[it] * 8)
                                 : *(const bf16x8*)(kpe + (size_t)kr[it] * 64 + (kg[it] - 16) * 8);
#pragma unroll
    for (int it = 0; it < 4; ++it)
        vreg[it] = *(const bf16x8*)(vt + (size_t)(h * 128 + vn[it]) * T + vkc[it] * 8);

    const int fgv = (quad ^ ((li >> 1) & 3)) * 8;
    const int kend = q0 + 64;
    for (int k0 = 0; k0 < kend; k0 += 64) {
        BAR_PLAIN();                            // all waves done reading LDS (prev iter)
#pragma unroll
        for (int it = 0; it < 6; ++it) *(bf16x8*)(Ks + kr[it] * 200 + kg[it] * 8) = kreg[it];
#pragma unroll
        for (int it = 0; it < 4; ++it)
            *(bf16x8*)(VtL[vgl[it] >> 2] + vn[it] * 32 + (vgl[it] & 3) * 8) = vreg[it];
        if (k0 + 64 < kend) {                   // prefetch next tile into regs (stays in flight)
            int k1 = k0 + 64;
#pragma unroll
            for (int it = 0; it < 6; ++it)
                kreg[it] = (kg[it] < 16) ? *(const bf16x8*)(kn + (size_t)(k1 + kr[it]) * (NH * 128) + h * 128 + kg[it] * 8)
                                         : *(const bf16x8*)(kpe + (size_t)(k1 + kr[it]) * 64 + (kg[it] - 16) * 8);
#pragma unroll
            for (int it = 0; it < 4; ++it)
                vreg[it] = *(const bf16x8*)(vt + (size_t)(h * 128 + vn[it]) * T + k1 + vkc[it] * 8);
        }
        BAR_LGKM0();                            // LDS tile visible; global prefetch NOT drained
        // S = Q K^T : 4 column sub-tiles of 16
        f32x4 s[4];
#pragma unroll
        for (int ct = 0; ct < 4; ++ct) {
            f32x4 a = (f32x4){0.f, 0.f, 0.f, 0.f};
#pragma unroll
            for (int s6 = 0; s6 < 6; ++s6) {
                bf16x8 kf = *(const bf16x8*)(Ks + (ct * 16 + li) * 200 + s6 * 32 + quad * 8);
                a = MFMA16(qf[s6], kf, a);
            }
            s[ct] = a;
        }
#pragma unroll
        for (int ct = 0; ct < 4; ++ct)
#pragma unroll
            for (int r = 0; r < 4; ++r) {
                int row = q0 + w * 16 + quad * 4 + r;
                float p = (k0 + ct * 16 + li <= row) ? __expf(s[ct][r] * scale) : 0.f;
                s[ct][r] = p;
                lrow[r] += p;
            }
        // P round trip: C-layout -> A-layout (wave-private rows; LDS per-wave in-order)
#pragma unroll
        for (int ct = 0; ct < 4; ++ct)
#pragma unroll
            for (int r = 0; r < 4; ++r)
                P[(w * 16 + quad * 4 + r) * 72 + ct * 16 + li] = f2bf(s[ct][r]);
        bf16x8 pf[2];
#pragma unroll
        for (int ks = 0; ks < 2; ++ks)
            pf[ks] = *(const bf16x8*)(P + (w * 16 + li) * 72 + ks * 32 + quad * 8);
#pragma unroll
        for (int v8 = 0; v8 < 8; ++v8)
#pragma unroll
            for (int ks = 0; ks < 2; ++ks) {
                bf16x8 vf = *(const bf16x8*)(VtL[ks] + (v8 * 16 + li) * 32 + fgv);
                accO[v8] = MFMA16(pf[ks], vf, accO[v8]);
            }
    }
#pragma unroll
    for (int r = 0; r < 4; ++r) {
        float l = lrow[r];
        l += __shfl_xor(l, 1); l += __shfl_xor(l, 2);
        l += __shfl_xor(l, 4); l += __shfl_xor(l, 8);
        lrow[r] = 1.0f / l;
    }
#pragma unroll
    for (int v8 = 0; v8 < 8; ++v8)
#pragma unroll
        for (int r = 0; r < 4; ++r) {
            float val = accO[v8][r] * lrow[r];
            O[(size_t)(q0 + w * 16 + quad * 4 + r) * (NH * 128) + h * 128 + v8 * 16 + li] = f2bf(val);
        }
}

// x2 = x1 + attn -> d_out ; n2_bf ; FUSED gate: top-2 over 8 experts (single-barrier reduce)
__global__ __launch_bounds__(256) void k_x2_n2(const float* __restrict__ x1, const bfu* __restrict__ attn,
                                               const float* __restrict__ ln2w, float* __restrict__ outx2,
                                               bfu* __restrict__ n2b, const float* __restrict__ gw,
                                               int* __restrict__ eidx, float* __restrict__ wts,
                                               int* __restrict__ cnt) {
    int t = blockIdx.x;
    size_t base = (size_t)t * H;
    float loc[8]; float ss = 0.f;
#pragma unroll
    for (int i = 0; i < 8; ++i) {
        int c = threadIdx.x + i * 256;
        float vv = x1[base + c] + bf2f(attn[base + c]);
        loc[i] = vv; ss += vv * vv;
        outx2[base + c] = vv;
    }
    float tot = blk_sum(ss);
    float r = rsqrtf(tot / (float)H + EPS);
    float pe[NE] = {0.f, 0.f, 0.f, 0.f, 0.f, 0.f, 0.f, 0.f};
#pragma unroll
    for (int i = 0; i < 8; ++i) {
        int c = threadIdx.x + i * 256;
        float nv = loc[i] * r * ln2w[c];
        n2b[base + c] = f2bf(nv);
#pragma unroll
        for (int e = 0; e < NE; ++e) pe[e] += nv * gw[e * H + c];
    }
    __shared__ float sred[4][NE];
    int lane = threadIdx.x & 63, wv = threadIdx.x >> 6;
#pragma unroll
    for (int e = 0; e < NE; ++e) {
        float v = pe[e];
        for (int o = 32; o > 0; o >>= 1) v += __shfl_down(v, o, 64);
        if (lane == 0) sred[wv][e] = v;
    }
    __syncthreads();
    if (threadIdx.x == 0) {
        float logits[NE];
        float m = -1e30f;
        for (int e = 0; e < NE; ++e) {
            logits[e] = sred[0][e] + sred[1][e] + sred[2][e] + sred[3][e];
            m = fmaxf(m, logits[e]);
        }
        float p[NE];
        for (int e = 0; e < NE; ++e) p[e] = __expf(logits[e] - m);
        int i1 = 0;
        for (int e = 1; e < NE; ++e) if (p[e] > p[i1]) i1 = e;
        int i2 = -1;
        for (int e = 0; e < NE; ++e) if (e != i1 && (i2 < 0 || p[e] > p[i2])) i2 = e;
        float denom = p[i1] + p[i2];
        eidx[t * 2] = i1; eidx[t * 2 + 1] = i2;
        wts[t * 2] = p[i1] / denom; wts[t * 2 + 1] = p[i2] / denom;
        atomicAdd(&cnt[i1], 1); atomicAdd(&cnt[i2], 1);
    }
}

// ================= MoE routing =================
__global__ __launch_bounds__(256) void k_moe_init(int* __restrict__ cnt, int* __restrict__ slot,
                                                  int* __restrict__ eid, int* __restrict__ idx,
                                                  float* __restrict__ aw) {
    int tid = threadIdx.x;
    if (tid < NE) { cnt[tid] = 0; slot[tid] = 0; }
    if (tid < 40) eid[tid] = 0;
    for (int i = tid; i < MAXA; i += 256) { idx[i] = 0; aw[i] = 0.f; }
}

__global__ __launch_bounds__(64) void k_moe_scan(const int* __restrict__ cnt, int* __restrict__ base,
                                                 int* __restrict__ eid) {
    if (threadIdx.x == 0) {
        int off = 0;
        for (int e = 0; e < NE; ++e) {
            base[e] = off;
            int nb = (cnt[e] + 127) >> 7;
            for (int j = 0; j < nb; ++j) eid[(off >> 7) + j] = e;
            off += nb << 7;
        }
    }
}

__global__ __launch_bounds__(256) void k_moe_scatter(const int* __restrict__ eidx, const float* __restrict__ wts,
                                                     const int* __restrict__ base, int* __restrict__ slot,
                                                     int* __restrict__ idx, float* __restrict__ aw,
                                                     int* __restrict__ posmap) {
    int t = blockIdx.x * 256 + threadIdx.x;
#pragma unroll
    for (int j = 0; j < 2; ++j) {
        int e = eidx[t * 2 + j];
        int p = base[e] + atomicAdd(&slot[e], 1);
        idx[p] = t; aw[p] = wts[t * 2 + j]; posmap[t * 2 + j] = p;
    }
}

// merged silu: blocks [0,T) = shared expert rows; blocks [T, T+MAXA) = sparse MoE rows
__global__ __launch_bounds__(256) void k_silu_both(const bfu* __restrict__ hsh, bfu* __restrict__ gsh,
                                                   const bfu* __restrict__ hsp, const float* __restrict__ aw,
                                                   bfu* __restrict__ gsp, int T) {
    int b = blockIdx.x;
    if (b < T) {
        const bfu* row = hsh + (size_t)b * 2048;
        bfu* grow = gsh + (size_t)b * 1024;
#pragma unroll
        for (int j = 0; j < 4; ++j) {
            int i = threadIdx.x + j * 256;
            float a = bf2f(row[i]), bb = bf2f(row[1024 + i]);
            grow[i] = f2bf(a / (1.0f + __expf(-a)) * bb);
        }
    } else {
        int row = b - T;
        float we = aw[row];
        const bfu* hr = hsp + (size_t)row * 1024;
        bfu* gr = gsp + (size_t)row * 512;
#pragma unroll
        for (int j = 0; j < 2; ++j) {
            int i = threadIdx.x + j * 256;
            float a = bf2f(hr[i]), bb = bf2f(hr[512 + i]);
            gr[i] = f2bf(we * a / (1.0f + __expf(-a)) * bb);
        }
    }
}

__global__ __launch_bounds__(256) void k_ffn_out(const float* __restrict__ routed, const bfu* __restrict__ dsp,
                                                 const int* __restrict__ posmap, float* __restrict__ out,
                                                 size_t TH) {
    int t = blockIdx.x;
    int p1 = posmap[t * 2], p2 = posmap[t * 2 + 1];
    const bfu* d1 = dsp + (size_t)p1 * H;
    const bfu* d2 = dsp + (size_t)p2 * H;
#pragma unroll
    for (int j = 0; j < 8; ++j) {
        int c = threadIdx.x + j * 256;
        out[TH + (size_t)t * H + c] = routed[(size_t)t * H + c] + bf2f(d1[c]) + bf2f(d2[c]);
    }
}

static inline GemmSeg mk_seg(const bfu* A, const bfu* B, void* C, void* C2,
                             const int* aidx, const int* eid, long bstride,
                             int N, int K, int ldm3, int mode, int nx, int ny) {
    GemmSeg s;
    s.A = A; s.B = B; s.C = C; s.C2 = C2; s.aidx = aidx; s.eid = eid; s.bstride = bstride;
    s.N = N; s.K = K; s.ldm3 = ldm3; s.mode = mode; s.nx = nx; s.ntiles = nx * ny;
    return s;
}

static inline CastArgs mk_cast(int n, const float* const ss[], bfu* const dd[],
                               const unsigned nn[], const int pp[]) {
    CastArgs ca;
    unsigned acc = 0;
    for (int i = 0; i < n; ++i) {
        ca.s[i] = ss[i]; ca.d[i] = dd[i]; ca.pad[i] = pp[i];
        ca.start[i] = acc; acc += nn[i];
    }
    for (int i = n; i < 10; ++i) {
        ca.s[i] = ss[n - 1]; ca.d[i] = dd[n - 1]; ca.pad[i] = 0; ca.start[i] = acc;
    }
    ca.start[10] = acc;
    return ca;
}

extern "C" void kernel_launch(void* const* d_in, const int* in_sizes, int n_in,
                              void* d_out, int out_size, void* d_ws, size_t ws_size,
                              hipStream_t stream) {
    const float* x      = (const float*)d_in[0];
    const float* skip   = (const float*)d_in[1];
    const float* rsin   = (const float*)d_in[2];
    const float* rcos   = (const float*)d_in[3];
    const float* ln1w   = (const float*)d_in[4];
    const float* ln2w   = (const float*)d_in[5];
    const float* w_qa   = (const float*)d_in[6];
    const float* qa_nw  = (const float*)d_in[7];
    const float* w_qb   = (const float*)d_in[8];
    const float* w_kva  = (const float*)d_in[9];
    const float* kva_nw = (const float*)d_in[10];
    const float* w_kb   = (const float*)d_in[11];
    const float* w_vb   = (const float*)d_in[12];
    const float* w_o    = (const float*)d_in[13];
    const float* gate_w = (const float*)d_in[14];
    const float* mup    = (const float*)d_in[15];
    const float* mdown  = (const float*)d_in[16];
    const float* shup   = (const float*)d_in[17];
    const float* shdown = (const float*)d_in[18];

    const int T = in_sizes[0] / H;   // 2048

    // ---- bf16 weight arena (element offsets) ----
    bfu* WB = (bfu*)d_ws;
    bfu* wqkv_b  = WB + 0;            // [2176][2048]: qa rows 0..1535, kva rows 1536..2175 (padded)
    bfu* wkbv_b  = WB + 4456448;      // [4096][512]: kb rows 0..2047, vb rows 2048..4095
    bfu* wqb_b   = WB + 6553600;      // [3072][1536]
    bfu* wo_b    = WB + 11272192;     // [2048][2048]
    bfu* mup_b   = WB + 15466496;     // [8][1024][2048]
    bfu* mdown_b = WB + 32243712;     // [8][2048][512]
    bfu* shup_b  = WB + 40632320;     // [2048][2048]
    bfu* shdn_b  = WB + 44826624;     // [2048][1024]
    const size_t WBYTES = 93847552;

    // ---- activation arena (byte offsets; lifetime-packed) ----
    char* AB = (char*)d_ws + WBYTES;
    float* x1f    = (float*)(AB + 0);           // A0 16MB: x1 (dead after x2_n2)
    float* routed = (float*)(AB + 0);           //   A0 reuse: shared-expert down out
    bfu*   n1b    = (bfu*)(AB + 16777216);      // A1 8MB: n1 -> n2 bf16
    bfu*   qkvb   = (bfu*)(AB + 25165824);      // A2 10.49MB: qkv bf16 [T][2176] (8.9MB)
    bfu*   knb    = (bfu*)(AB + 25165824);      //   A2 reuse: k_nope (8MB)
    bfu*   hsp    = (bfu*)(AB + 25165824);      //   A2 reuse: MoE up out (10.49MB)
    bfu*   qab    = (bfu*)(AB + 35651584);      // A3 6.29MB: qa normed
    bfu*   gsp    = (bfu*)(AB + 35651584);      //   A3 reuse: MoE silu out (5.24MB)
    bfu*   qbb    = (bfu*)(AB + 41943040);      // A4 12.58MB: q bf16
    bfu*   attnb  = (bfu*)(AB + 41943040);      //   A4 reuse: attn bf16 (8MB)
    bfu*   ckvb   = (bfu*)(AB + 54525952);      // A5 2.10MB
    bfu*   kpeb   = (bfu*)(AB + 56623104);      // A6 0.26MB
    char*  G      = AB + 56885248;              // gate/routing arrays (128KB)
    int*   eidx   = (int*)(G);
    float* wts    = (float*)(G + 16384);
    int*   posmap = (int*)(G + 32768);
    int*   midx   = (int*)(G + 49152);
    float* maw    = (float*)(G + 69632);
    int*   mcnt   = (int*)(G + 90112);
    int*   mbase  = (int*)(G + 90112 + 64);
    int*   mslot  = (int*)(G + 90112 + 128);
    int*   meid   = (int*)(G + 90112 + 192);
    bfu*   ob     = (bfu*)(AB + 57016320);      // A7 8.39MB: attention O
    bfu*   gsb    = (bfu*)(AB + 57016320);      //   A7 reuse: shared silu out
    bfu*   vtb    = (bfu*)(AB + 65404928);      // A8 20.97MB: V^T (8.39MB)
    bfu*   hsb    = (bfu*)(AB + 65404928);      //   A8 reuse: shared up out (8.39MB)
    bfu*   dsp    = (bfu*)(AB + 65404928);      //   A8 reuse: MoE down out (20.97MB)
    const size_t REQ = WBYTES + 86376448;       // ~180.2 MB
    if (ws_size < REQ) return;

    GemmSeg z; z.A = nullptr; z.B = nullptr; z.C = nullptr; z.C2 = nullptr;
    z.aidx = nullptr; z.eid = nullptr; z.bstride = 0;
    z.N = 0; z.K = 32; z.ldm3 = 0; z.mode = 1; z.nx = 1; z.ntiles = 0;

    // cast plans (granule-16 counts): tensors are cast in the latest dispatch that still
    // precedes their first use, hiding cast latency under GEMM compute.
    const float* c0s[2] = {w_qa, w_kva};
    bfu*         c0d[2] = {wqkv_b, wqkv_b + 3145728};
    unsigned     c0n[2] = {196608, 81920};
    int          c0p[2] = {0, 1};
    CastArgs ca0 = mk_cast(2, c0s, c0d, c0n, c0p);            // 278528 g -> 1088 blocks

    const float* cQs[3] = {w_qb, w_kb, w_vb};
    bfu*         cQd[3] = {wqb_b, wkbv_b, wkbv_b + 1048576};
    unsigned     cQn[3] = {294912, 65536, 65536};
    int          cQp[3] = {0, 0, 0};
    CastArgs caQ = mk_cast(3, cQs, cQd, cQn, cQp);            // 425984 g -> 1664 blocks

    const float* cBs[2] = {w_o, mup};
    bfu*         cBd[2] = {wo_b, mup_b};
    unsigned     cBn[2] = {262144, 1048576};
    int          cBp[2] = {0, 0};
    CastArgs caB = mk_cast(2, cBs, cBd, cBn, cBp);            // 1310720 g -> 5120 blocks

    const float* cWs[3] = {shup, mdown, shdown};
    bfu*         cWd[3] = {shup_b, mdown_b, shdn_b};
    unsigned     cWn[3] = {262144, 524288, 131072};
    int          cWp[3] = {0, 0, 0};
    CastArgs caW = mk_cast(3, cWs, cWd, cWn, cWp);            // 917504 g -> 3584 blocks

    const float* cEs[1] = {w_qa}; bfu* cEd[1] = {wqkv_b};
    unsigned cEn[1] = {0}; int cEp[1] = {0};
    CastArgs caE = mk_cast(1, cEs, cEd, cEn, cEp);            // empty

    // 0) cast qa+kva only (must precede qkv GEMM)
    gemm_multi<<<1088, 256, 0, stream>>>(z, z, ca0);
    // 1) x1, n1
    k_add_rms<<<T, 256, 0, stream>>>(x, skip, ln1w, x1f, n1b);
    // 2) qkv GEMM (272 tiles) + cast{w_qb, w_kb, w_vb}
    {
        GemmSeg s = mk_seg(n1b, wqkv_b, qkvb, nullptr, nullptr, nullptr, 0, 2176, H, 0, 1, 2176 / 128, T / 128);
        gemm_multi<<<s.ntiles + 1664, 256, 0, stream>>>(s, z, caQ);
    }
    k_qkv_post<<<T, 256, 0, stream>>>(qkvb, qa_nw, kva_nw, rsin, rcos, qab, ckvb, kpeb);
    // 3+4) q GEMM || kbv GEMM (896 tiles) + cast{w_o, mup}
    {
        GemmSeg sq = mk_seg(qab, wqb_b, qbb, nullptr, nullptr, nullptr, 0, NH * DQK, QL, 0, 1, (NH * DQK) / 128, T / 128);
        GemmSeg sk = mk_seg(ckvb, wkbv_b, knb, vtb, nullptr, nullptr, 0, 4096, KVL, T, 4, 4096 / 128, T / 128);
        gemm_multi<<<sq.ntiles + sk.ntiles + 5120, 256, 0, stream>>>(sq, sk, caB);
    }
    // 5) flash attention v2 -> O bf16 (64-row q blocks, 64-row KV tiles)
    k_flash_mfma<<<dim3(T / 64, NH), 256, 0, stream>>>(qbb, knb, kpeb, vtb, ob, rsin, rcos, T);
    // 6) attn = O @ w_o^T (256 tiles) + cast{shup, mdown, shdown}
    {
        GemmSeg s = mk_seg(ob, wo_b, attnb, nullptr, nullptr, nullptr, 0, H, NH * VD, 0, 1, H / 128, T / 128);
        gemm_multi<<<s.ntiles + 3584, 256, 0, stream>>>(s, z, caW);
    }
    // 7) routing init + x2/n2/gate fused
    k_moe_init<<<1, 256, 0, stream>>>(mcnt, mslot, meid, midx, maw);
    k_x2_n2<<<T, 256, 0, stream>>>(x1f, attnb, ln2w, (float*)d_out, n1b, gate_w, eidx, wts, mcnt);
    k_moe_scan<<<1, 64, 0, stream>>>(mcnt, mbase, meid);
    k_moe_scatter<<<T / 256, 256, 0, stream>>>(eidx, wts, mbase, mslot, midx, maw, posmap);
    // 8+9a) MERGED: shared-up || sparse MoE up (both read n2)
    {
        GemmSeg ssh = mk_seg(n1b, shup_b, hsb, nullptr, nullptr, nullptr, 0, 2048, H, 0, 1, 2048 / 128, T / 128);
        GemmSeg smo = mk_seg(n1b, mup_b, hsp, nullptr, midx, meid, (long)1024 * H, 1024, H, 0, 1, 1024 / 128, MAXA / 128);
        gemm_multi<<<ssh.ntiles + smo.ntiles, 256, 0, stream>>>(ssh, smo, caE);
    }
    // silu (shared + sparse in one dispatch)
    k_silu_both<<<T + MAXA, 256, 0, stream>>>(hsb, gsb, hsp, maw, gsp, T);
    // 8b+9b) MERGED: shared-down (f32) || sparse MoE down
    {
        GemmSeg ssd = mk_seg(gsb, shdn_b, routed, nullptr, nullptr, nullptr, 0, H, SHI, 0, 0, H / 128, T / 128);
        GemmSeg smd = mk_seg(gsp, mdown_b, dsp, nullptr, nullptr, meid, (long)H * MI_D, H, MI_D, 0, 1, H / 128, MAXA / 128);
        gemm_multi<<<ssd.ntiles + smd.ntiles, 256, 0, stream>>>(ssd, smd, caE);
    }
    // 10) ffn writeout
    k_ffn_out<<<T, 256, 0, stream>>>(routed, dsp, posmap, (float*)d_out, (size_t)T * H);
}